// Round 1
// baseline (274.819 us; speedup 1.0000x reference)
//
#include <hip/hip_runtime.h>

// DerivativeNet direction='x': B=16,C=2,H=1024,W=1024 fp32.
// One wave (64 lanes) per row; no LDS, no __syncthreads.
// Each lane owns 4 interleaved float4 chunks: chunk c covers elements
// [c*256, c*256+256), lane l owns elements c*256 + 4l .. +3  (coalesced).
// Mask cumsum = 4 intra-wave shuffle scans; halos via shfl + boundary bcast.

typedef float v4f __attribute__((ext_vector_type(4)));

__global__ __launch_bounds__(256) void deriv_x_kernel(
    const float* __restrict__ u,
    const float* __restrict__ mask,
    float* __restrict__ out)
{
    const int lane = threadIdx.x & 63;
    const int row  = (blockIdx.x << 2) + (threadIdx.x >> 6);   // b*1024 + y
    const int b    = row >> 10;
    const int y    = row & 1023;

    const size_t moff  = (size_t)row << 10;                    // mask[b,0,y,:]
    const size_t u0off = ((size_t)b << 21) + ((size_t)y << 10);// u[b,0,y,:]
    const size_t u1off = u0off + (size_t)(1 << 20);            // u[b,1,y,:]

    const float4* mp  = (const float4*)(mask + moff);
    const float4* u0p = (const float4*)(u + u0off);
    const float4* u1p = (const float4*)(u + u1off);

    // ---- issue all 12 loads up-front (mask first so its vmcnt clears first)
    float4 m4[4], a4[4], c4[4];
    #pragma unroll
    for (int c = 0; c < 4; ++c) m4[c] = mp[(c << 6) + lane];
    #pragma unroll
    for (int c = 0; c < 4; ++c) a4[c] = u0p[(c << 6) + lane];
    #pragma unroll
    for (int c = 0; c < 4; ++c) c4[c] = u1p[(c << 6) + lane];

    // ---- mask bits as ints (exact vs reference float cumsum: max 1024)
    int i0[4], i1[4], i2[4], i3[4], cnt[4];
    #pragma unroll
    for (int c = 0; c < 4; ++c) {
        i0[c] = (int)m4[c].x; i1[c] = (int)m4[c].y;
        i2[c] = (int)m4[c].z; i3[c] = (int)m4[c].w;
        cnt[c] = i0[c] + i1[c] + i2[c] + i3[c];
    }

    // ---- per-chunk inclusive shuffle scan over 64 lanes
    int excl[4], ctot[4];
    #pragma unroll
    for (int c = 0; c < 4; ++c) {
        int v = cnt[c];
        #pragma unroll
        for (int off = 1; off < 64; off <<= 1) {
            int n = __shfl_up(v, off);
            if (lane >= off) v += n;
        }
        excl[c] = v - cnt[c];        // exclusive prefix within chunk
        ctot[c] = __shfl(v, 63);     // chunk total (broadcast)
    }
    const int total = ctot[0] + ctot[1] + ctot[2] + ctot[3];

    const float inv2h = 50.0f;    // 1/(2h), h=0.01
    const float invh  = 100.0f;   // 1/h

    v4f* o0p = (v4f*)(out + u0off);
    v4f* o1p = (v4f*)(out + u1off);

    int basec = 0;
    #pragma unroll
    for (int c = 0; c < 4; ++c) {
        // cumsum at the 4 owned elements
        const int cs0 = basec + excl[c] + i0[c];
        const int cs1 = cs0 + i1[c];
        const int cs2 = cs1 + i2[c];
        const int cs3 = cs2 + i3[c];

        // neighbor mask bits (zero-pad at row ends)
        int ml = __shfl_up(i3[c], 1);
        {
            int mlc = __shfl(i3[c == 0 ? 0 : c - 1], 63);
            if (c == 0) mlc = 0;
            if (lane == 0) ml = mlc;
        }
        int mr = __shfl_down(i0[c], 1);
        {
            int mrc = __shfl(i0[c == 3 ? 3 : c + 1], 0);
            if (c == 3) mrc = 0;
            if (lane == 63) mr = mrc;
        }

        // eroded: 3-box == 3
        const float er0 = (ml    + i0[c] + i1[c] == 3) ? 1.f : 0.f;
        const float er1 = (i0[c] + i1[c] + i2[c] == 3) ? 1.f : 0.f;
        const float er2 = (i1[c] + i2[c] + i3[c] == 3) ? 1.f : 0.f;
        const float er3 = (i2[c] + i3[c] + mr    == 3) ? 1.f : 0.f;

        // edge1: cs == 1 ; edge2: cs == total && mask
        const float e10 = (cs0 == 1) ? 1.f : 0.f;
        const float e11 = (cs1 == 1) ? 1.f : 0.f;
        const float e12 = (cs2 == 1) ? 1.f : 0.f;
        const float e13 = (cs3 == 1) ? 1.f : 0.f;
        const float e20 = (i0[c] && cs0 == total) ? 1.f : 0.f;
        const float e21 = (i1[c] && cs1 == total) ? 1.f : 0.f;
        const float e22 = (i2[c] && cs2 == total) ? 1.f : 0.f;
        const float e23 = (i3[c] && cs3 == total) ? 1.f : 0.f;

#define DO_CH(V, VPREV, VNEXT, OP)                                                 \
        {                                                                          \
            float ul = __shfl_up(V.w, 1);                                          \
            float ulc = __shfl(VPREV.w, 63);                                       \
            if (c == 0) ulc = 0.f;                                                 \
            if (lane == 0) ul = ulc;                                               \
            float ur = __shfl_down(V.x, 1);                                        \
            float urc = __shfl(VNEXT.x, 0);                                        \
            if (c == 3) urc = 0.f;                                                 \
            if (lane == 63) ur = urc;                                              \
            v4f o;                                                                 \
            o.x = er0*((V.y - ul )*inv2h) + e10*((V.y - V.x)*invh) + e20*((V.x - ul )*invh); \
            o.y = er1*((V.z - V.x)*inv2h) + e11*((V.z - V.y)*invh) + e21*((V.y - V.x)*invh); \
            o.z = er2*((V.w - V.y)*inv2h) + e12*((V.w - V.z)*invh) + e22*((V.z - V.y)*invh); \
            o.w = er3*((ur  - V.z)*inv2h) + e13*((ur  - V.w)*invh) + e23*((V.w - V.z)*invh); \
            __builtin_nontemporal_store(o, &OP[(c << 6) + lane]);                  \
        }

        DO_CH(a4[c], a4[c == 0 ? 0 : c - 1], a4[c == 3 ? 3 : c + 1], o0p)
        DO_CH(c4[c], c4[c == 0 ? 0 : c - 1], c4[c == 3 ? 3 : c + 1], o1p)
#undef DO_CH

        basec += ctot[c];
    }
}

extern "C" void kernel_launch(void* const* d_in, const int* in_sizes, int n_in,
                              void* d_out, int out_size, void* d_ws, size_t ws_size,
                              hipStream_t stream) {
    const float* u    = (const float*)d_in[0];
    const float* mask = (const float*)d_in[1];
    float* out        = (float*)d_out;
    // 16*1024 rows, one wave per row, 4 waves (256 threads) per block
    deriv_x_kernel<<<dim3(4096), dim3(256), 0, stream>>>(u, mask, out);
}

// Round 2
// 270.108 us; speedup vs baseline: 1.0174x; 1.0174x over previous
//
#include <hip/hip_runtime.h>

// DerivativeNet direction='x': B=16,C=2,H=1024,W=1024 fp32.
// One wave (64 lanes) per row; no LDS, no __syncthreads.
// Chunk c covers elements [c*256, c*256+256); lane l owns 4 consecutive
// elements c*256 + 4l .. +3 (float4, coalesced).
// Mask logic is done entirely with wave ballots + 64-bit scalar mask
// algebra + v_mbcnt prefix counts: zero DS ops, zero latency chains.
// Only the float halo exchange uses shuffles (16 independent bpermutes).

typedef float v4f __attribute__((ext_vector_type(4)));

__device__ __forceinline__ int prefix_below(unsigned long long m) {
    // popcount of m restricted to lanes strictly below this lane
    return (int)__builtin_amdgcn_mbcnt_hi(
        (unsigned)(m >> 32),
        __builtin_amdgcn_mbcnt_lo((unsigned)(m & 0xffffffffull), 0u));
}

__global__ __launch_bounds__(256, 4) void deriv_x_kernel(
    const float* __restrict__ u,
    const float* __restrict__ mask,
    float* __restrict__ out)
{
    const int lane = threadIdx.x & 63;
    const int row  = (blockIdx.x << 2) + (threadIdx.x >> 6);   // b*1024 + y
    const int b    = row >> 10;
    const int y    = row & 1023;

    const size_t moff  = (size_t)row << 10;                     // mask[b,0,y,:]
    const size_t u0off = ((size_t)b << 21) + ((size_t)y << 10); // u[b,0,y,:]
    const size_t u1off = u0off + (size_t)(1 << 20);             // u[b,1,y,:]

    const float4* mp  = (const float4*)(mask + moff);
    const float4* u0p = (const float4*)(u + u0off);
    const float4* u1p = (const float4*)(u + u1off);

    // ---- issue all 12 loads up-front; mask first (its consumers come first)
    float4 m4[4], a4[4], c4[4];
    #pragma unroll
    for (int c = 0; c < 4; ++c) m4[c] = mp[(c << 6) + lane];
    #pragma unroll
    for (int c = 0; c < 4; ++c) a4[c] = u0p[(c << 6) + lane];
    #pragma unroll
    for (int c = 0; c < 4; ++c) c4[c] = u1p[(c << 6) + lane];

    // ---- mask bits + ballots (uniform 64-bit masks, one per sub-element)
    int i0[4], i1[4], i2[4], i3[4];
    unsigned long long B0[4], B1[4], B2[4], B3[4];
    #pragma unroll
    for (int c = 0; c < 4; ++c) {
        i0[c] = (m4[c].x != 0.f);
        i1[c] = (m4[c].y != 0.f);
        i2[c] = (m4[c].z != 0.f);
        i3[c] = (m4[c].w != 0.f);
        B0[c] = __ballot(i0[c]);
        B1[c] = __ballot(i1[c]);
        B2[c] = __ballot(i2[c]);
        B3[c] = __ballot(i3[c]);
    }

    // ---- scalar mask algebra: chunk totals, row total
    int tot[4];
    #pragma unroll
    for (int c = 0; c < 4; ++c)
        tot[c] = __popcll(B0[c]) + __popcll(B1[c]) + __popcll(B2[c]) + __popcll(B3[c]);
    const int total = tot[0] + tot[1] + tot[2] + tot[3];

    const float inv2h = 50.0f;    // 1/(2h), h=0.01
    const float invh  = 100.0f;   // 1/h

    v4f* o0p = (v4f*)(out + u0off);
    v4f* o1p = (v4f*)(out + u1off);

    int basec = 0;
    #pragma unroll
    for (int c = 0; c < 4; ++c) {
        // neighbor masks via scalar shifts (zero-pad at row ends)
        const unsigned long long lcarry =
            (c > 0) ? (B3[c - 1] >> 63) : 0ull;                 // bit63 of prev chunk
        const unsigned long long rcarry =
            (c < 3) ? ((B0[c + 1] & 1ull) << 63) : 0ull;        // bit0 of next chunk
        const unsigned long long L0 = (B3[c] << 1) | lcarry;    // mask at element-1
        const unsigned long long R3 = (B0[c] >> 1) | rcarry;    // mask at element+4

        // eroded 3-box == all three set: pure 64-bit ANDs
        const unsigned long long E0 = L0    & B0[c] & B1[c];
        const unsigned long long E1 = B0[c] & B1[c] & B2[c];
        const unsigned long long E2 = B1[c] & B2[c] & B3[c];
        const unsigned long long E3 = B2[c] & B3[c] & R3;

        const float er0 = ((E0 >> lane) & 1ull) ? 1.f : 0.f;
        const float er1 = ((E1 >> lane) & 1ull) ? 1.f : 0.f;
        const float er2 = ((E2 >> lane) & 1ull) ? 1.f : 0.f;
        const float er3 = ((E3 >> lane) & 1ull) ? 1.f : 0.f;

        // cumsum: chunk base (scalar) + prefix below lane (mbcnt) + own bits
        const int excl = prefix_below(B0[c]) + prefix_below(B1[c]) +
                         prefix_below(B2[c]) + prefix_below(B3[c]);
        const int cs0 = basec + excl + i0[c];
        const int cs1 = cs0 + i1[c];
        const int cs2 = cs1 + i2[c];
        const int cs3 = cs2 + i3[c];

        const float e10 = (cs0 == 1) ? 1.f : 0.f;
        const float e11 = (cs1 == 1) ? 1.f : 0.f;
        const float e12 = (cs2 == 1) ? 1.f : 0.f;
        const float e13 = (cs3 == 1) ? 1.f : 0.f;
        const float e20 = (i0[c] && cs0 == total) ? 1.f : 0.f;
        const float e21 = (i1[c] && cs1 == total) ? 1.f : 0.f;
        const float e22 = (i2[c] && cs2 == total) ? 1.f : 0.f;
        const float e23 = (i3[c] && cs3 == total) ? 1.f : 0.f;

#define DO_CH(V, VPREV, VNEXT, OP)                                                 \
        {                                                                          \
            float ul  = __shfl_up(V.w, 1);                                         \
            float ulb = __shfl(VPREV.w, 63);   /* prev-chunk lane63 broadcast */   \
            if (c == 0) ulb = 0.f;                                                 \
            if (lane == 0) ul = ulb;                                               \
            float ur  = __shfl_down(V.x, 1);                                       \
            float urb = __shfl(VNEXT.x, 0);    /* next-chunk lane0 broadcast */    \
            if (c == 3) urb = 0.f;                                                 \
            if (lane == 63) ur = urb;                                              \
            v4f o;                                                                 \
            o.x = er0*((V.y - ul )*inv2h) + e10*((V.y - V.x)*invh) + e20*((V.x - ul )*invh); \
            o.y = er1*((V.z - V.x)*inv2h) + e11*((V.z - V.y)*invh) + e21*((V.y - V.x)*invh); \
            o.z = er2*((V.w - V.y)*inv2h) + e12*((V.w - V.z)*invh) + e22*((V.z - V.y)*invh); \
            o.w = er3*((ur  - V.z)*inv2h) + e13*((ur  - V.w)*invh) + e23*((V.w - V.z)*invh); \
            OP[(c << 6) + lane] = o;                                               \
        }

        DO_CH(a4[c], a4[c == 0 ? 0 : c - 1], a4[c == 3 ? 3 : c + 1], o0p)
        DO_CH(c4[c], c4[c == 0 ? 0 : c - 1], c4[c == 3 ? 3 : c + 1], o1p)
#undef DO_CH

        basec += tot[c];
    }
}

extern "C" void kernel_launch(void* const* d_in, const int* in_sizes, int n_in,
                              void* d_out, int out_size, void* d_ws, size_t ws_size,
                              hipStream_t stream) {
    const float* u    = (const float*)d_in[0];
    const float* mask = (const float*)d_in[1];
    float* out        = (float*)d_out;
    // 16*1024 rows, one wave per row, 4 waves (256 threads) per block
    deriv_x_kernel<<<dim3(4096), dim3(256), 0, stream>>>(u, mask, out);
}

// Round 3
// 264.902 us; speedup vs baseline: 1.0374x; 1.0197x over previous
//
#include <hip/hip_runtime.h>

// DerivativeNet direction='x': B=16,C=2,H=1024,W=1024 fp32.
// Hybrid: one block (256 thr = 4 waves) per row for max wave concurrency,
// ballot/mbcnt mask algebra (no shuffle-scan chains), zero data staging in
// LDS (28 B of cross-wave glue + ONE barrier; all LDS reads broadcast).
// Each thread owns 4 consecutive elements (one float4 per array).

typedef float v4f __attribute__((ext_vector_type(4)));

__device__ __forceinline__ int prefix_below(unsigned long long m) {
    // popcount of m over lanes strictly below this lane
    return (int)__builtin_amdgcn_mbcnt_hi(
        (unsigned)(m >> 32),
        __builtin_amdgcn_mbcnt_lo((unsigned)(m & 0xffffffffull), 0u));
}

__global__ __launch_bounds__(256) void deriv_x_kernel(
    const float* __restrict__ u,
    const float* __restrict__ mask,
    float* __restrict__ out)
{
    const int tid  = threadIdx.x;        // 0..255, owns elements 4tid..4tid+3
    const int lane = tid & 63;
    const int wave = tid >> 6;
    const int row  = blockIdx.x;         // b*1024 + y
    const int b    = row >> 10;
    const int y    = row & 1023;

    const size_t moff  = (size_t)row << 10;                     // mask[b,0,y,:]
    const size_t u0off = ((size_t)b << 21) + ((size_t)y << 10); // u[b,0,y,:]
    const size_t u1off = u0off + (size_t)(1 << 20);             // u[b,1,y,:]

    // ---- 3 coalesced float4 loads per thread, all independent, issued up-front
    const float4 m4 = ((const float4*)(mask + moff))[tid];
    const float4 a4 = ((const float4*)(u + u0off))[tid];
    const float4 c4 = ((const float4*)(u + u1off))[tid];

    // ---- per-wave ballots (uniform 64-bit masks in SGPRs)
    const int i0 = (m4.x != 0.f), i1 = (m4.y != 0.f);
    const int i2 = (m4.z != 0.f), i3 = (m4.w != 0.f);
    const unsigned long long B0 = __ballot(i0);
    const unsigned long long B1 = __ballot(i1);
    const unsigned long long B2 = __ballot(i2);
    const unsigned long long B3 = __ballot(i3);

    const int wtot = __popcll(B0) + __popcll(B1) + __popcll(B2) + __popcll(B3);

    // ---- cross-wave glue (28 B): totals, boundary mask bits, boundary floats
    __shared__ int   s_tot[4];    // per-wave mask count
    __shared__ int   s_b3[4];     // bit63 of B3  (mask at wave's last element)
    __shared__ int   s_b0[4];     // bit0  of B0  (mask at wave's first element)
    __shared__ float s_last0[4], s_last1[4];    // u[.,wave end]   per channel
    __shared__ float s_first0[4], s_first1[4];  // u[.,wave start] per channel

    if (lane == 0) {
        s_tot[wave]    = wtot;
        s_b3[wave]     = (int)(B3 >> 63);
        s_b0[wave]     = (int)(B0 & 1ull);
        s_first0[wave] = a4.x;
        s_first1[wave] = c4.x;
    }
    if (lane == 63) {
        s_last0[wave] = a4.w;
        s_last1[wave] = c4.w;
    }

    __syncthreads();   // the only barrier

    const int t0 = s_tot[0], t1 = s_tot[1], t2 = s_tot[2], t3 = s_tot[3];
    const int total = t0 + t1 + t2 + t3;
    int base = 0;
    if (wave > 0) base += t0;
    if (wave > 1) base += t1;
    if (wave > 2) base += t2;

    const int lcbit = (wave > 0) ? s_b3[wave - 1] : 0;   // mask left of wave
    const int rcbit = (wave < 3) ? s_b0[wave + 1] : 0;   // mask right of wave
    const float ulb0 = (wave > 0) ? s_last0[wave - 1] : 0.f;
    const float ulb1 = (wave > 0) ? s_last1[wave - 1] : 0.f;
    const float urb0 = (wave < 3) ? s_first0[wave + 1] : 0.f;
    const float urb1 = (wave < 3) ? s_first1[wave + 1] : 0.f;

    // ---- eroded 3-box via 64-bit mask algebra
    const unsigned long long L0 = (B3 << 1) | (unsigned long long)lcbit;
    const unsigned long long R3 = (B0 >> 1) | ((unsigned long long)rcbit << 63);
    const unsigned long long E0 = L0 & B0 & B1;
    const unsigned long long E1 = B0 & B1 & B2;
    const unsigned long long E2 = B1 & B2 & B3;
    const unsigned long long E3 = B2 & B3 & R3;

    const float er0 = ((E0 >> lane) & 1ull) ? 1.f : 0.f;
    const float er1 = ((E1 >> lane) & 1ull) ? 1.f : 0.f;
    const float er2 = ((E2 >> lane) & 1ull) ? 1.f : 0.f;
    const float er3 = ((E3 >> lane) & 1ull) ? 1.f : 0.f;

    // ---- inclusive cumsum at the 4 owned elements (exact integer)
    const int excl = base + prefix_below(B0) + prefix_below(B1) +
                            prefix_below(B2) + prefix_below(B3);
    const int cs0 = excl + i0;
    const int cs1 = cs0 + i1;
    const int cs2 = cs1 + i2;
    const int cs3 = cs2 + i3;

    const float e10 = (cs0 == 1) ? 1.f : 0.f;
    const float e11 = (cs1 == 1) ? 1.f : 0.f;
    const float e12 = (cs2 == 1) ? 1.f : 0.f;
    const float e13 = (cs3 == 1) ? 1.f : 0.f;
    const float e20 = (i0 && cs0 == total) ? 1.f : 0.f;
    const float e21 = (i1 && cs1 == total) ? 1.f : 0.f;
    const float e22 = (i2 && cs2 == total) ? 1.f : 0.f;
    const float e23 = (i3 && cs3 == total) ? 1.f : 0.f;

    const float inv2h = 50.0f;    // 1/(2h), h=0.01
    const float invh  = 100.0f;   // 1/h

#define DO_CH(V, ULB, URB, OFF)                                                    \
    {                                                                              \
        float ul = __shfl_up(V.w, 1);                                              \
        if (lane == 0) ul = ULB;                                                   \
        float ur = __shfl_down(V.x, 1);                                            \
        if (lane == 63) ur = URB;                                                  \
        v4f o;                                                                     \
        o.x = er0*((V.y - ul )*inv2h) + e10*((V.y - V.x)*invh) + e20*((V.x - ul )*invh); \
        o.y = er1*((V.z - V.x)*inv2h) + e11*((V.z - V.y)*invh) + e21*((V.y - V.x)*invh); \
        o.z = er2*((V.w - V.y)*inv2h) + e12*((V.w - V.z)*invh) + e22*((V.z - V.y)*invh); \
        o.w = er3*((ur  - V.z)*inv2h) + e13*((ur  - V.w)*invh) + e23*((V.w - V.z)*invh); \
        ((v4f*)(out + OFF))[tid] = o;                                              \
    }

    DO_CH(a4, ulb0, urb0, u0off)
    DO_CH(c4, ulb1, urb1, u1off)
#undef DO_CH
}

extern "C" void kernel_launch(void* const* d_in, const int* in_sizes, int n_in,
                              void* d_out, int out_size, void* d_ws, size_t ws_size,
                              hipStream_t stream) {
    const float* u    = (const float*)d_in[0];
    const float* mask = (const float*)d_in[1];
    float* out        = (float*)d_out;
    // one block per (b,y) row: 16*1024 blocks, 256 threads each
    deriv_x_kernel<<<dim3(16 * 1024), dim3(256), 0, stream>>>(u, mask, out);
}